// Round 13
// baseline (3727.253 us; speedup 1.0000x reference)
//
#include <hip/hip_runtime.h>

#define T_LEN 16384
#define BATCH 32
#define HID 32
#define L2E 1.44269504088896340736f

typedef float f2 __attribute__((ext_vector_type(2)));
typedef unsigned u2_t __attribute__((ext_vector_type(2)));

#if __has_builtin(__builtin_amdgcn_exp2f)
#define EXP2F(x) __builtin_amdgcn_exp2f(x)
#else
#define EXP2F(x) __exp2f(x)
#endif
#if __has_builtin(__builtin_amdgcn_rcpf)
#define RCPF(x) __builtin_amdgcn_rcpf(x)
#else
#define RCPF(x) (1.0f / (x))
#endif

__device__ __forceinline__ float rlane(float v, int lane) {
    return __int_as_float(__builtin_amdgcn_readlane(__float_as_int(v), lane));
}

// own + partner(lane^32), all lanes. Calibrated r4/r5: permlane32_swap with
// both args = v returns r.x = {v_lo, v_lo}, r.y = {v_hi, v_hi}; so
// r.x + r.y = v[lane] + v[lane^32] in every lane — no select needed.
__device__ __forceinline__ float xhalf_sum(float v) {
#if __has_builtin(__builtin_amdgcn_permlane32_swap)
    u2_t r = __builtin_amdgcn_permlane32_swap(__float_as_uint(v), __float_as_uint(v),
                                              false, false);
    return __uint_as_float(r.x) + __uint_as_float(r.y);
#else
    return v + __shfl_xor(v, 32, 64);
#endif
}

// r13: K-split restructure. Lane j and lane 32+j BOTH own all 4 gate rows of
// unit j; lower lanes compute the K=[0,16) partial dot, upper lanes K=[16,32).
//  - LDS broadcast reads halve (each lane reads only its K-half of h; the
//    two halves' addresses are a 2-way broadcast = free, m136)
//  - partials combine with ONE permlane32_swap + add per row (r.x+r.y trick)
//  - i,f,g,o,c,h all lane-local: the cross-half u-ship is GONE from the chain
//  - W/b pre-scaled by -log2e*{1,2}: activations are rcp(1+exp2(z')) direct
// h ends up replicated in both halves; publish/flush logic unchanged.
__global__ __launch_bounds__(64) __attribute__((amdgpu_waves_per_eu(1, 1)))
void lstm_seq_kernel(const float* __restrict__ x,
                     const float* __restrict__ W_ih,
                     const float* __restrict__ W_hh,
                     const float* __restrict__ b_ih,
                     const float* __restrict__ b_hh,
                     const float* __restrict__ W_out,
                     const float* __restrict__ b_out,
                     float* __restrict__ out)
{
    const int b    = blockIdx.x;
    const int lane = threadIdx.x;
    const int j    = lane & 31;          // my hidden unit (both halves)
    const int kbase = (lane & 32) >> 1;  // 0 for lanes 0-31, 16 for 32-63

    // torch gate rows: i=j, f=32+j, g=64+j, o=96+j. Pre-scaled:
    // sigmoid rows (i,f,o) by -L2E; tanh row (g) by -2*L2E.
    const float sclS = -L2E;
    const float sclG = -2.0f * L2E;

    f2 Wi2[8], Wf2[8], Wg2[8], Wo2[8];
    {
        const f2* ri = (const f2*)(W_hh + (size_t)(     j) * HID + kbase);
        const f2* rf = (const f2*)(W_hh + (size_t)(32 + j) * HID + kbase);
        const f2* rg = (const f2*)(W_hh + (size_t)(64 + j) * HID + kbase);
        const f2* ro = (const f2*)(W_hh + (size_t)(96 + j) * HID + kbase);
        #pragma unroll
        for (int p = 0; p < 8; ++p) {
            Wi2[p] = ri[p] * sclS;
            Wf2[p] = rf[p] * sclS;
            Wg2[p] = rg[p] * sclG;
            Wo2[p] = ro[p] * sclS;
        }
    }
    #pragma unroll
    for (int p = 0; p < 8; ++p) {
        asm("" : "+v"(Wi2[p]), "+v"(Wf2[p]), "+v"(Wg2[p]), "+v"(Wo2[p]));
    }

    // x weights / biases, pre-scaled; HALVED because both K-halves add their
    // xb into the combined sum (own + partner => xb counted twice).
    const float wih_i = 0.5f * sclS * W_ih[j];
    const float wih_f = 0.5f * sclS * W_ih[32 + j];
    const float wih_g = 0.5f * sclG * W_ih[64 + j];
    const float wih_o = 0.5f * sclS * W_ih[96 + j];
    const float bi = 0.5f * sclS * (b_ih[     j] + b_hh[     j]);
    const float bf = 0.5f * sclS * (b_ih[32 + j] + b_hh[32 + j]);
    const float bg = 0.5f * sclG * (b_ih[64 + j] + b_hh[64 + j]);
    const float bo = 0.5f * sclS * (b_ih[96 + j] + b_hh[96 + j]);

    const float wout = W_out[j];
    const float bout = b_out[0];

    // phist[s][lane], stride 65; flush reads columns 0..31 (lower copies).
    __shared__ float phist[64 * 65];
    __shared__ float hbuf[64];

    float c = 0.0f, h = 0.0f;   // replicated state in both halves
    hbuf[lane] = 0.0f;          // seed h_0 = 0
    __syncthreads();

    const float* xb_ptr = x + (size_t)b * T_LEN;
    float*       yb     = out + (size_t)b * T_LEN;
    // my K-half of the h vector, as f2 pairs (2-way broadcast reads)
    const f2* hb2 = reinterpret_cast<const f2*>(&hbuf[kbase]);

    float xv = xb_ptr[lane];  // 64 timesteps of x per lane-chunk

    for (int t0 = 0; t0 < T_LEN; t0 += 64) {
        float xv_next = (t0 + 64 < T_LEN) ? xb_ptr[t0 + 64 + lane] : 0.0f;

        #pragma unroll 4
        for (int s = 0; s < 64; ++s) {
            // off-chain: x+bias per row (pre-scaled, halved for double-count)
            const float xs  = rlane(xv, s);
            const float xbi = fmaf(xs, wih_i, bi);
            const float xbf = fmaf(xs, wih_f, bf);
            const float xbg = fmaf(xs, wih_g, bg);
            const float xbo = fmaf(xs, wih_o, bo);

            // my K-half of h: 8 f2 broadcast reads (2 addr groups: free)
            f2 hv2[8];
            #pragma unroll
            for (int p = 0; p < 8; ++p) hv2[p] = hb2[p];

            // 4 rows x 8 pk_fma, 2-way split chains per row
            f2 ai0, ai1, af0, af1, ag0, ag1, ao0, ao1;
            asm("v_pk_mul_f32 %0, %1, %2" : "=v"(ai0) : "v"(hv2[0]), "v"(Wi2[0]));
            asm("v_pk_mul_f32 %0, %1, %2" : "=v"(ai1) : "v"(hv2[1]), "v"(Wi2[1]));
            asm("v_pk_mul_f32 %0, %1, %2" : "=v"(af0) : "v"(hv2[0]), "v"(Wf2[0]));
            asm("v_pk_mul_f32 %0, %1, %2" : "=v"(af1) : "v"(hv2[1]), "v"(Wf2[1]));
            asm("v_pk_mul_f32 %0, %1, %2" : "=v"(ag0) : "v"(hv2[0]), "v"(Wg2[0]));
            asm("v_pk_mul_f32 %0, %1, %2" : "=v"(ag1) : "v"(hv2[1]), "v"(Wg2[1]));
            asm("v_pk_mul_f32 %0, %1, %2" : "=v"(ao0) : "v"(hv2[0]), "v"(Wo2[0]));
            asm("v_pk_mul_f32 %0, %1, %2" : "=v"(ao1) : "v"(hv2[1]), "v"(Wo2[1]));
            #pragma unroll
            for (int p = 2; p < 8; p += 2) {
                asm("v_pk_fma_f32 %0, %1, %2, %0" : "+v"(ai0) : "v"(hv2[p  ]), "v"(Wi2[p  ]));
                asm("v_pk_fma_f32 %0, %1, %2, %0" : "+v"(ai1) : "v"(hv2[p+1]), "v"(Wi2[p+1]));
                asm("v_pk_fma_f32 %0, %1, %2, %0" : "+v"(af0) : "v"(hv2[p  ]), "v"(Wf2[p  ]));
                asm("v_pk_fma_f32 %0, %1, %2, %0" : "+v"(af1) : "v"(hv2[p+1]), "v"(Wf2[p+1]));
                asm("v_pk_fma_f32 %0, %1, %2, %0" : "+v"(ag0) : "v"(hv2[p  ]), "v"(Wg2[p  ]));
                asm("v_pk_fma_f32 %0, %1, %2, %0" : "+v"(ag1) : "v"(hv2[p+1]), "v"(Wg2[p+1]));
                asm("v_pk_fma_f32 %0, %1, %2, %0" : "+v"(ao0) : "v"(hv2[p  ]), "v"(Wo2[p  ]));
                asm("v_pk_fma_f32 %0, %1, %2, %0" : "+v"(ao1) : "v"(hv2[p+1]), "v"(Wo2[p+1]));
            }
            const f2 Pi = ai0 + ai1, Pf = af0 + af1, Pg = ag0 + ag1, Po = ao0 + ao1;
            // partial (this K-half) + xb; cross-half combine sums both halves
            const float pi = Pi.x + Pi.y + xbi;
            const float pf = Pf.x + Pf.y + xbf;
            const float pg = Pg.x + Pg.y + xbg;
            const float po = Po.x + Po.y + xbo;

            const float zi = xhalf_sum(pi);   // pre-scaled full gate inputs
            const float zf = xhalf_sum(pf);
            const float zg = xhalf_sum(pg);
            const float zo = xhalf_sum(po);

            const float si = RCPF(1.0f + EXP2F(zi));                 // sigmoid
            const float sf = RCPF(1.0f + EXP2F(zf));
            const float tg = fmaf(2.0f, RCPF(1.0f + EXP2F(zg)), -1.0f); // tanh
            const float so = RCPF(1.0f + EXP2F(zo));

            c = fmaf(sf, c, si * tg);
            const float th = fmaf(2.0f, RCPF(1.0f + EXP2F(sclG * c)), -1.0f);
            h = so * th;

            hbuf[lane] = h;                    // publish (gates next step)
            phist[s * 65 + lane] = h * wout;   // deferred output (off-chain)
        }

        __syncthreads();  // single wave: cheap; publish phist
        float acc = bout;
        #pragma unroll
        for (int k = 0; k < HID; ++k) acc += phist[lane * 65 + k];
        yb[t0 + lane] = acc;
        __syncthreads();  // protect phist before next chunk rewrites it

        xv = xv_next;
    }
}

extern "C" void kernel_launch(void* const* d_in, const int* in_sizes, int n_in,
                              void* d_out, int out_size, void* d_ws, size_t ws_size,
                              hipStream_t stream) {
    const float* x     = (const float*)d_in[0];
    const float* W_ih  = (const float*)d_in[1];
    const float* W_hh  = (const float*)d_in[2];
    const float* b_ih  = (const float*)d_in[3];
    const float* b_hh  = (const float*)d_in[4];
    const float* W_out = (const float*)d_in[5];
    const float* b_out = (const float*)d_in[6];
    float* out = (float*)d_out;

    lstm_seq_kernel<<<BATCH, 64, 0, stream>>>(x, W_ih, W_hh, b_ih, b_hh,
                                              W_out, b_out, out);
}

// Round 14
// 3069.668 us; speedup vs baseline: 1.2142x; 1.2142x over previous
//
#include <hip/hip_runtime.h>

#define T_LEN 16384
#define BATCH 32
#define HID 32
#define L2E 1.44269504088896340736f
#define SCLG (-2.0f * 1.44269504088896340736f)   // -2*log2e

typedef float f2 __attribute__((ext_vector_type(2)));
typedef unsigned u2_t __attribute__((ext_vector_type(2)));

#if __has_builtin(__builtin_amdgcn_exp2f)
#define EXP2F(x) __builtin_amdgcn_exp2f(x)
#else
#define EXP2F(x) __exp2f(x)
#endif
#if __has_builtin(__builtin_amdgcn_rcpf)
#define RCPF(x) __builtin_amdgcn_rcpf(x)
#else
#define RCPF(x) (1.0f / (x))
#endif

__device__ __forceinline__ float rlane(float v, int lane) {
    return __int_as_float(__builtin_amdgcn_readlane(__float_as_int(v), lane));
}

// Cross-half exchange (lower->upper), VALU pipe. Convention verified r4/r5:
// builtin returns {vdst_new, vsrc_new}; r.x has lanes 32-63 = old lanes 0-31.
__device__ __forceinline__ float xhalf_lo_to_hi(float v) {
#if __has_builtin(__builtin_amdgcn_permlane32_swap)
    u2_t r = __builtin_amdgcn_permlane32_swap(__float_as_uint(v), __float_as_uint(v),
                                              false, false);
    return __uint_as_float(r.x);
#else
    return __shfl_xor(v, 32, 64);
#endif
}

// r14 = r12 (best: 3182us) + activation-tail chain trims. r13's K-split
// regressed (same pk_fma count, +4 chain swaps) — reverted.
//  1. W/b pre-scaled by -log2e (A rows: i,f,o-side) / -2log2e (g): the
//     dependent -z*L2E muls between dot and exp2 are gone.
//  2. Scaled cell cS = -2log2e*c: update cS = fma(sf, cS, u') with
//     u' = -2log2e*u computed on the LOWER half pre-ship (chain-neutral
//     there) -> exp2(cS) direct, no mul after the c-update.
//  3. h = fma(2so, r2, -so): one fma after the tanh-rcp (2so precomputed
//     while the c-chain drains; neg modifier free).
__global__ __launch_bounds__(64) __attribute__((amdgpu_waves_per_eu(1, 1)))
void lstm_seq_kernel(const float* __restrict__ x,
                     const float* __restrict__ W_ih,
                     const float* __restrict__ W_hh,
                     const float* __restrict__ b_ih,
                     const float* __restrict__ b_hh,
                     const float* __restrict__ W_out,
                     const float* __restrict__ b_out,
                     float* __restrict__ out)
{
    const int b    = blockIdx.x;
    const int lane = threadIdx.x;
    const int j    = lane & 31;
    const bool upper = (lane >= 32);

    // torch gate order in W_ih/W_hh rows: [0,32)=i [32,64)=f [64,96)=g [96,128)=o
    const int rowA = upper ? (32 + j) : j;        // f : i   (both sigmoid)
    const int rowB = upper ? (96 + j) : (64 + j); // o : g   (sigmoid : tanh)

    // Pre-scale: sigmoid rows by -L2E; tanh row (g, lower B) by -2*L2E.
    const float sclA = -L2E;
    const float sclB = upper ? -L2E : SCLG;

    // W rows as float2 pairs (pre-scaled), pinned resident (r9/r12)
    f2 Wa2[16], Wb2[16];
    const f2* ra2 = reinterpret_cast<const f2*>(W_hh + (size_t)rowA * HID);
    const f2* rb2 = reinterpret_cast<const f2*>(W_hh + (size_t)rowB * HID);
    #pragma unroll
    for (int q = 0; q < 16; ++q) { Wa2[q] = ra2[q] * sclA; Wb2[q] = rb2[q] * sclB; }
    #pragma unroll
    for (int q = 0; q < 16; ++q) { asm("" : "+v"(Wa2[q]), "+v"(Wb2[q])); }

    const float wihA = sclA * W_ih[rowA];
    const float wihB = sclB * W_ih[rowB];
    const float bA = sclA * (b_ih[rowA] + b_hh[rowA]);
    const float bB = sclB * (b_ih[rowB] + b_hh[rowB]);

    // B-gate shaping: Bv = r*mB + aB  (tanh: 2r-1 on lower; sigmoid on upper)
    const float mB = upper ? 1.0f : 2.0f;
    const float aB = upper ? 0.0f : -1.0f;

    const float wout = W_out[j];
    const float bout = b_out[0];

    // phist[s][lane], stride 65: store banks (s+l)%32 conflict-free;
    // flush read phist[l*65+32+k] banks (l+k)%32 conflict-free.
    __shared__ float phist[64 * 65];
    // h-broadcast buffer: slot per lane; upper 32 slots [32..63] hold h_j.
    __shared__ float hbuf[64];

    float cS = 0.0f, h = 0.0f;   // cS = -2log2e * c, state in upper lanes
    hbuf[lane] = 0.0f;           // seed h_0 = 0
    __syncthreads();

    const float* xb = x + (size_t)b * T_LEN;
    float*       yb = out + (size_t)b * T_LEN;
    // wave-uniform broadcast-read base (h values live at hbuf[32..63]),
    // read as f2 pairs -> register pairs that ARE the pk_fma operands.
    const f2* hb2 = reinterpret_cast<const f2*>(&hbuf[32]);

    float xv = xb[lane];  // 64 timesteps of x per lane-chunk

    for (int t0 = 0; t0 < T_LEN; t0 += 64) {
        float xv_next = (t0 + 64 < T_LEN) ? xb[t0 + 64 + lane] : 0.0f;

        #pragma unroll 4
        for (int s = 0; s < 64; ++s) {
            // x contribution: independent of h, schedules off-chain
            const float xs  = rlane(xv, s);
            const float xpA = fmaf(xs, wihA, bA);
            const float xpB = fmaf(xs, wihB, bB);

            // broadcast read: 16 f2 loads, wave-uniform, conflict-free,
            // pipelined; each lands as an even-aligned VGPR pair.
            f2 hv2[16];
            #pragma unroll
            for (int p = 0; p < 16; ++p) hv2[p] = hb2[p];

            // dots: 32 pure-VGPR v_pk_fma_f32, 4-way split accumulators.
            f2 zA[4], zB[4];
            #pragma unroll
            for (int p = 0; p < 16; ++p) {
                if (p < 4) {
                    asm("v_pk_mul_f32 %0, %1, %2"
                        : "=v"(zA[p]) : "v"(hv2[p]), "v"(Wa2[p]));
                    asm("v_pk_mul_f32 %0, %1, %2"
                        : "=v"(zB[p]) : "v"(hv2[p]), "v"(Wb2[p]));
                } else {
                    asm("v_pk_fma_f32 %0, %1, %2, %0"
                        : "+v"(zA[p & 3]) : "v"(hv2[p]), "v"(Wa2[p]));
                    asm("v_pk_fma_f32 %0, %1, %2, %0"
                        : "+v"(zB[p & 3]) : "v"(hv2[p]), "v"(Wb2[p]));
                }
            }
            const f2 rA = (zA[0] + zA[1]) + (zA[2] + zA[3]);
            const f2 rB = (zB[0] + zB[1]) + (zB[2] + zB[3]);
            const float za = (rA.x + rA.y) + xpA;   // pre-scaled gate input
            const float zb = (rB.x + rB.y) + xpB;   // pre-scaled gate input

            // A = sigmoid (i lower / f upper): rcp(1+exp2(za)) — no mul
            const float A  = RCPF(1.0f + EXP2F(za));
            const float r  = RCPF(1.0f + EXP2F(zb));
            const float Bv = fmaf(r, mB, aB);       // tanh(g) : sigmoid(o)
            const float Bv2 = Bv + Bv;              // 2so (upper), off-chain

            // lower: u' = -2log2e * (si*tg); ship to upper (VALU swap)
            const float u  = A * Bv;
            const float up = u * SCLG;
            const float tu = xhalf_lo_to_hi(up);

            // upper: cS = sf*cS + (-2log2e)(si*tg); tanh(c) via exp2(cS) direct
            cS = fmaf(A, cS, tu);
            const float r2 = RCPF(1.0f + EXP2F(cS));
            h = fmaf(Bv2, r2, -Bv);                 // so*tanh(c), single fma

            hbuf[lane] = h;                    // publish FIRST (gates next step)
            phist[s * 65 + lane] = h * wout;   // deferred output (off-chain)
        }

        __syncthreads();  // single wave: cheap; publish phist
        float acc = bout;
        #pragma unroll
        for (int k = 0; k < HID; ++k) acc += phist[lane * 65 + 32 + k];
        yb[t0 + lane] = acc;
        __syncthreads();  // protect phist before next chunk rewrites it

        xv = xv_next;
    }
}

extern "C" void kernel_launch(void* const* d_in, const int* in_sizes, int n_in,
                              void* d_out, int out_size, void* d_ws, size_t ws_size,
                              hipStream_t stream) {
    const float* x     = (const float*)d_in[0];
    const float* W_ih  = (const float*)d_in[1];
    const float* W_hh  = (const float*)d_in[2];
    const float* b_ih  = (const float*)d_in[3];
    const float* b_hh  = (const float*)d_in[4];
    const float* W_out = (const float*)d_in[5];
    const float* b_out = (const float*)d_in[6];
    float* out = (float*)d_out;

    lstm_seq_kernel<<<BATCH, 64, 0, stream>>>(x, W_ih, W_hh, b_ih, b_hh,
                                              W_out, b_out, out);
}